// Round 6
// baseline (227.983 us; speedup 1.0000x reference)
//
#include <hip/hip_runtime.h>

#define HW (512 * 512)
#define GD 200
#define NS 9
#define NF 8
#define NPB 64              // rays per block
#define BT 320              // 5 waves; thread (r,k): r=tid/5, k=tid%5 -> samples {2k,2k+1}, k=4 -> {8,8}

__global__ __launch_bounds__(BT) void fusion_gather_kernel(
    const float* __restrict__ vpoints,
    const float* __restrict__ veye,
    const float* __restrict__ grid,
    const float* __restrict__ empty_value,
    float* __restrict__ out_values,   // [72][HW]
    float* __restrict__ out_pn,       // [HW][9][3]
    float* __restrict__ out_dirs)     // [HW][3]
{
    __shared__ float vbuf[NS * NF * 65];     // [72][65]: bank=(row+col)%32, 2-way on row-read = free
    __shared__ float pnbuf[NPB * 27];        // [r][s][c]
    __shared__ float dirbuf[NPB * 3];        // 26.4 KB total -> 6 blocks/CU (30 waves)

    int tid = threadIdx.x;
    int r = tid / 5;
    int k = tid - r * 5;
    int n0 = blockIdx.x * NPB;
    int n = n0 + r;

    float px = vpoints[n * 3 + 0];
    float py = vpoints[n * 3 + 1];
    float pz = vpoints[n * 3 + 2];
    float ex = veye[0], ey = veye[1], ez = veye[2];

    float dx = px - ex, dy = py - ey, dz = pz - ez;
    float inv = 1.0f / sqrtf(dx * dx + dy * dy + dz * dz);
    dx *= inv; dy *= inv; dz *= inv;

    if (k == 0) {
        dirbuf[r * 3 + 0] = dx;
        dirbuf[r * 3 + 1] = dy;
        dirbuf[r * 3 + 2] = dz;
    }

    int sA = (k < 4) ? 2 * k : 8;
    int sB = (k < 4) ? 2 * k + 1 : 8;   // k==4 redoes sample 8: branch-free, dup loads are L1 hits

    const float4* __restrict__ g4 = (const float4*)grid;

    // ---------------- per-sample address setup ----------------
    float cxA = px + (float)(sA - 4) * dx, cyA = py + (float)(sA - 4) * dy, czA = pz + (float)(sA - 4) * dz;
    float cxB = px + (float)(sB - 4) * dx, cyB = py + (float)(sB - 4) * dy, czB = pz + (float)(sB - 4) * dz;

    pnbuf[r * 27 + sA * 3 + 0] = cxA - (floorf(cxA) + 0.5f);
    pnbuf[r * 27 + sA * 3 + 1] = cyA - (floorf(cyA) + 0.5f);
    pnbuf[r * 27 + sA * 3 + 2] = czA - (floorf(czA) + 0.5f);
    pnbuf[r * 27 + sB * 3 + 0] = cxB - (floorf(cxB) + 0.5f);
    pnbuf[r * 27 + sB * 3 + 1] = cyB - (floorf(cyB) + 0.5f);
    pnbuf[r * 27 + sB * 3 + 2] = czB - (floorf(czB) + 0.5f);

    bool vA = (cxA >= 0.0f) && (cxA < (float)GD) && (cyA >= 0.0f) && (cyA < (float)GD) &&
              (czA >= 0.0f) && (czA < (float)GD);
    bool vB = (cxB >= 0.0f) && (cxB < (float)GD) && (cyB >= 0.0f) && (cyB < (float)GD) &&
              (czB >= 0.0f) && (czB < (float)GD);

    // reference: p = pts + 1 into edge-padded grid; padded idx j -> grid[clamp(j-1,0,199)]
    float pA0 = cxA + 1.0f, pA1 = cyA + 1.0f, pA2 = czA + 1.0f;
    float fA0 = floorf(pA0), fA1 = floorf(pA1), fA2 = floorf(pA2);
    float dA0 = pA0 - fA0, dA1 = pA1 - fA1, dA2 = pA2 - fA2;
    int bxA = (int)fA0, byA = (int)fA1, bzA = (int)fA2;
    int XA0 = min(max(bxA - 1, 0), GD - 1), XA1 = min(max(bxA, 0), GD - 1);
    int YA0 = min(max(byA - 1, 0), GD - 1), YA1 = min(max(byA, 0), GD - 1);
    int ZA0 = min(max(bzA - 1, 0), GD - 1), ZA1 = min(max(bzA, 0), GD - 1);

    float pB0 = cxB + 1.0f, pB1 = cyB + 1.0f, pB2 = czB + 1.0f;
    float fB0 = floorf(pB0), fB1 = floorf(pB1), fB2 = floorf(pB2);
    float dB0 = pB0 - fB0, dB1 = pB1 - fB1, dB2 = pB2 - fB2;
    int bxB = (int)fB0, byB = (int)fB1, bzB = (int)fB2;
    int XB0 = min(max(bxB - 1, 0), GD - 1), XB1 = min(max(bxB, 0), GD - 1);
    int YB0 = min(max(byB - 1, 0), GD - 1), YB1 = min(max(byB, 0), GD - 1);
    int ZB0 = min(max(bzB - 1, 0), GD - 1), ZB1 = min(max(bzB, 0), GD - 1);

    int colA[4], colB[4];
    colA[0] = (XA0 * GD + YA0) * GD; colA[1] = (XA0 * GD + YA1) * GD;
    colA[2] = (XA1 * GD + YA0) * GD; colA[3] = (XA1 * GD + YA1) * GD;
    colB[0] = (XB0 * GD + YB0) * GD; colB[1] = (XB0 * GD + YB1) * GD;
    colB[2] = (XB1 * GD + YB0) * GD; colB[3] = (XB1 * GD + YB1) * GD;

    // ---------------- load phase: 32 independent 16B gathers ----------------
    float4 cA[16], cB[16];
#pragma unroll
    for (int q = 0; q < 4; ++q) {
        cA[q * 4 + 0] = g4[(size_t)(colA[q] + ZA0) * 2 + 0];
        cA[q * 4 + 1] = g4[(size_t)(colA[q] + ZA0) * 2 + 1];
        cA[q * 4 + 2] = g4[(size_t)(colA[q] + ZA1) * 2 + 0];
        cA[q * 4 + 3] = g4[(size_t)(colA[q] + ZA1) * 2 + 1];
    }
#pragma unroll
    for (int q = 0; q < 4; ++q) {
        cB[q * 4 + 0] = g4[(size_t)(colB[q] + ZB0) * 2 + 0];
        cB[q * 4 + 1] = g4[(size_t)(colB[q] + ZB0) * 2 + 1];
        cB[q * 4 + 2] = g4[(size_t)(colB[q] + ZB1) * 2 + 0];
        cB[q * 4 + 3] = g4[(size_t)(colB[q] + ZB1) * 2 + 1];
    }

    float ev[NF];
#pragma unroll
    for (int f = 0; f < NF; ++f) ev[f] = empty_value[f];

    // ---------------- compute + stage sample A ----------------
    {
        float wx0 = 1.0f - dA0, wy0 = 1.0f - dA1, wz0 = 1.0f - dA2;
        float wq[4] = {wx0 * wy0, wx0 * dA1, dA0 * wy0, dA0 * dA1};
        float acc[NF];
#pragma unroll
        for (int f = 0; f < NF; ++f) acc[f] = 0.0f;
#pragma unroll
        for (int q = 0; q < 4; ++q) {
            float w0 = wq[q] * wz0, w1 = wq[q] * dA2;
            acc[0] += w0 * cA[q * 4 + 0].x + w1 * cA[q * 4 + 2].x;
            acc[1] += w0 * cA[q * 4 + 0].y + w1 * cA[q * 4 + 2].y;
            acc[2] += w0 * cA[q * 4 + 0].z + w1 * cA[q * 4 + 2].z;
            acc[3] += w0 * cA[q * 4 + 0].w + w1 * cA[q * 4 + 2].w;
            acc[4] += w0 * cA[q * 4 + 1].x + w1 * cA[q * 4 + 3].x;
            acc[5] += w0 * cA[q * 4 + 1].y + w1 * cA[q * 4 + 3].y;
            acc[6] += w0 * cA[q * 4 + 1].z + w1 * cA[q * 4 + 3].z;
            acc[7] += w0 * cA[q * 4 + 1].w + w1 * cA[q * 4 + 3].w;
        }
#pragma unroll
        for (int f = 0; f < NF; ++f)
            vbuf[(sA * NF + f) * 65 + r] = vA ? acc[f] : ev[f];
    }

    // ---------------- compute + stage sample B ----------------
    {
        float wx0 = 1.0f - dB0, wy0 = 1.0f - dB1, wz0 = 1.0f - dB2;
        float wq[4] = {wx0 * wy0, wx0 * dB1, dB0 * wy0, dB0 * dB1};
        float acc[NF];
#pragma unroll
        for (int f = 0; f < NF; ++f) acc[f] = 0.0f;
#pragma unroll
        for (int q = 0; q < 4; ++q) {
            float w0 = wq[q] * wz0, w1 = wq[q] * dB2;
            acc[0] += w0 * cB[q * 4 + 0].x + w1 * cB[q * 4 + 2].x;
            acc[1] += w0 * cB[q * 4 + 0].y + w1 * cB[q * 4 + 2].y;
            acc[2] += w0 * cB[q * 4 + 0].z + w1 * cB[q * 4 + 2].z;
            acc[3] += w0 * cB[q * 4 + 0].w + w1 * cB[q * 4 + 2].w;
            acc[4] += w0 * cB[q * 4 + 1].x + w1 * cB[q * 4 + 3].x;
            acc[5] += w0 * cB[q * 4 + 1].y + w1 * cB[q * 4 + 3].y;
            acc[6] += w0 * cB[q * 4 + 1].z + w1 * cB[q * 4 + 3].z;
            acc[7] += w0 * cB[q * 4 + 1].w + w1 * cB[q * 4 + 3].w;
        }
#pragma unroll
        for (int f = 0; f < NF; ++f)
            vbuf[(sB * NF + f) * 65 + r] = vB ? acc[f] : ev[f];
    }

    __syncthreads();

    // ---------------- block-coalesced writeout ----------------
    // values: 4608 floats; per instr a lane-run covers full 64-col rows (2-way LDS bank alias = free)
#pragma unroll
    for (int j = 0; j < 15; ++j) {
        int idx = tid + j * BT;
        if (idx < NS * NF * 64) {
            int row = idx >> 6, col = idx & 63;
            __builtin_nontemporal_store(vbuf[row * 65 + col],
                                        &out_values[(size_t)row * HW + n0 + col]);
        }
    }
    // pn: 1728 floats
    const size_t pn_base = (size_t)n0 * 27;
#pragma unroll
    for (int j = 0; j < 6; ++j) {
        int idx = tid + j * BT;
        if (idx < NPB * 27)
            __builtin_nontemporal_store(pnbuf[idx], &out_pn[pn_base + idx]);
    }
    if (tid < NPB * 3)
        __builtin_nontemporal_store(dirbuf[tid], &out_dirs[(size_t)n0 * 3 + tid]);
}

extern "C" void kernel_launch(void* const* d_in, const int* in_sizes, int n_in,
                              void* d_out, int out_size, void* d_ws, size_t ws_size,
                              hipStream_t stream) {
    const float* vpoints = (const float*)d_in[0];
    const float* veye = (const float*)d_in[1];
    // d_in[2] = depth: unused (shape only)
    const float* grid = (const float*)d_in[3];
    const float* empty_value = (const float*)d_in[4];

    float* out = (float*)d_out;
    float* out_values = out;                          // 72 * HW
    float* out_pn = out + (size_t)NS * NF * HW;       // HW * 9 * 3
    float* out_dirs = out_pn + (size_t)HW * NS * 3;   // HW * 3

    dim3 block(BT);
    dim3 grid_dim(HW / NPB);
    hipLaunchKernelGGL(fusion_gather_kernel, grid_dim, block, 0, stream,
                       vpoints, veye, grid, empty_value,
                       out_values, out_pn, out_dirs);
}

// Round 7
// 171.404 us; speedup vs baseline: 1.3301x; 1.3301x over previous
//
#include <hip/hip_runtime.h>

#define HW (512 * 512)
#define GD 200
#define NS 9
#define NF 8
#define NPB 28              // rays per block (7 per wave)
#define BT 256              // 4 waves: lane = r*9+s (r 0..6, s 0..8), lane 63 idle
#define P 29                // vbuf padded leading dim

__global__ __launch_bounds__(BT) void fusion_gather_kernel(
    const float* __restrict__ vpoints,
    const float* __restrict__ veye,
    const float* __restrict__ grid,
    const float* __restrict__ empty_value,
    float* __restrict__ out_values,   // [72][HW]
    float* __restrict__ out_pn,       // [HW][9][3]
    float* __restrict__ out_dirs)     // [HW][3]
{
    __shared__ float vbuf[NS * NF * P];     // [72][29] staged values
    __shared__ float pnbuf[NPB * 27];       // [r][s][c]
    __shared__ float dirbuf[NPB * 3];       // total ~11.7 KB -> 8 blocks/CU possible

    int tid = threadIdx.x;
    int w = tid >> 6;
    int l = tid & 63;
    int n0 = blockIdx.x * NPB;
    int nvalid = min(NPB, HW - n0);         // tail block handling

    if (l < 63) {
        int r = l / 9;
        int s = l - r * 9;
        int lr = w * 7 + r;                 // local ray 0..27
        if (lr < nvalid) {
            int n = n0 + lr;

            float px = vpoints[n * 3 + 0];
            float py = vpoints[n * 3 + 1];
            float pz = vpoints[n * 3 + 2];
            float ex = veye[0], ey = veye[1], ez = veye[2];

            float dx = px - ex, dy = py - ey, dz = pz - ez;
            float inv = 1.0f / sqrtf(dx * dx + dy * dy + dz * dz);
            dx *= inv; dy *= inv; dz *= inv;

            if (s == 0) {
                dirbuf[lr * 3 + 0] = dx;
                dirbuf[lr * 3 + 1] = dy;
                dirbuf[lr * 3 + 2] = dz;
            }

            float off = (float)(s - NS / 2);
            float cx = px + off * dx;
            float cy = py + off * dy;
            float cz = pz + off * dz;

            pnbuf[lr * 27 + s * 3 + 0] = cx - (floorf(cx) + 0.5f);
            pnbuf[lr * 27 + s * 3 + 1] = cy - (floorf(cy) + 0.5f);
            pnbuf[lr * 27 + s * 3 + 2] = cz - (floorf(cz) + 0.5f);

            bool valid = (cx >= 0.0f) && (cx < (float)GD) &&
                         (cy >= 0.0f) && (cy < (float)GD) &&
                         (cz >= 0.0f) && (cz < (float)GD);

            // reference: p = pts + 1 into edge-padded grid; padded idx j -> grid[clamp(j-1,0,199)]
            // Clamp unconditionally; invalid lanes load in-bounds, result replaced at store.
            float p0 = cx + 1.0f, p1 = cy + 1.0f, p2 = cz + 1.0f;
            float f0 = floorf(p0), f1 = floorf(p1), f2 = floorf(p2);
            float d0 = p0 - f0, d1 = p1 - f1, d2 = p2 - f2;
            int bx = (int)f0, by = (int)f1, bz = (int)f2;
            int X0 = min(max(bx - 1, 0), GD - 1), X1 = min(max(bx, 0), GD - 1);
            int Y0 = min(max(by - 1, 0), GD - 1), Y1 = min(max(by, 0), GD - 1);
            int Z0 = min(max(bz - 1, 0), GD - 1), Z1 = min(max(bz, 0), GD - 1);

            const float4* __restrict__ g4 = (const float4*)grid;

            // ---- load phase: all 16 independent 16B gathers before any consume ----
            int col[4];
            col[0] = (X0 * GD + Y0) * GD;
            col[1] = (X0 * GD + Y1) * GD;
            col[2] = (X1 * GD + Y0) * GD;
            col[3] = (X1 * GD + Y1) * GD;

            float4 c[16];
#pragma unroll
            for (int q = 0; q < 4; ++q) {
                c[q * 4 + 0] = g4[(size_t)(col[q] + Z0) * 2 + 0];
                c[q * 4 + 1] = g4[(size_t)(col[q] + Z0) * 2 + 1];
                c[q * 4 + 2] = g4[(size_t)(col[q] + Z1) * 2 + 0];
                c[q * 4 + 3] = g4[(size_t)(col[q] + Z1) * 2 + 1];
            }

            float wx0 = 1.0f - d0, wy0 = 1.0f - d1, wz0 = 1.0f - d2;
            float wq[4] = {wx0 * wy0, wx0 * d1, d0 * wy0, d0 * d1};

            float acc[NF];
#pragma unroll
            for (int f = 0; f < NF; ++f) acc[f] = 0.0f;

#pragma unroll
            for (int q = 0; q < 4; ++q) {
                float w0 = wq[q] * wz0, w1 = wq[q] * d2;
                acc[0] += w0 * c[q * 4 + 0].x + w1 * c[q * 4 + 2].x;
                acc[1] += w0 * c[q * 4 + 0].y + w1 * c[q * 4 + 2].y;
                acc[2] += w0 * c[q * 4 + 0].z + w1 * c[q * 4 + 2].z;
                acc[3] += w0 * c[q * 4 + 0].w + w1 * c[q * 4 + 2].w;
                acc[4] += w0 * c[q * 4 + 1].x + w1 * c[q * 4 + 3].x;
                acc[5] += w0 * c[q * 4 + 1].y + w1 * c[q * 4 + 3].y;
                acc[6] += w0 * c[q * 4 + 1].z + w1 * c[q * 4 + 3].z;
                acc[7] += w0 * c[q * 4 + 1].w + w1 * c[q * 4 + 3].w;
            }

            float ev[NF];
#pragma unroll
            for (int f = 0; f < NF; ++f) ev[f] = empty_value[f];

#pragma unroll
            for (int f = 0; f < NF; ++f)
                vbuf[(s * NF + f) * P + lr] = valid ? acc[f] : ev[f];
        }
    }

    __syncthreads();

    // ---- block-coalesced writeout ----
    // values: 72 rows x 28 cols = 2016 floats
#pragma unroll
    for (int j = 0; j < 8; ++j) {
        int idx = tid + j * BT;
        if (idx < NS * NF * NPB) {
            int row = idx / NPB;
            int col = idx - row * NPB;
            if (col < nvalid)
                __builtin_nontemporal_store(vbuf[row * P + col],
                                            &out_values[(size_t)row * HW + n0 + col]);
        }
    }
    // pn: up to 756 floats, contiguous
    const size_t pn_base = (size_t)n0 * 27;
#pragma unroll
    for (int j = 0; j < 3; ++j) {
        int idx = tid + j * BT;
        if (idx < nvalid * 27)
            __builtin_nontemporal_store(pnbuf[idx], &out_pn[pn_base + idx]);
    }
    if (tid < nvalid * 3)
        __builtin_nontemporal_store(dirbuf[tid], &out_dirs[(size_t)n0 * 3 + tid]);
}

extern "C" void kernel_launch(void* const* d_in, const int* in_sizes, int n_in,
                              void* d_out, int out_size, void* d_ws, size_t ws_size,
                              hipStream_t stream) {
    const float* vpoints = (const float*)d_in[0];
    const float* veye = (const float*)d_in[1];
    // d_in[2] = depth: unused (shape only)
    const float* grid = (const float*)d_in[3];
    const float* empty_value = (const float*)d_in[4];

    float* out = (float*)d_out;
    float* out_values = out;                          // 72 * HW
    float* out_pn = out + (size_t)NS * NF * HW;       // HW * 9 * 3
    float* out_dirs = out_pn + (size_t)HW * NS * 3;   // HW * 3

    dim3 block(BT);
    dim3 grid_dim((HW + NPB - 1) / NPB);
    hipLaunchKernelGGL(fusion_gather_kernel, grid_dim, block, 0, stream,
                       vpoints, veye, grid, empty_value,
                       out_values, out_pn, out_dirs);
}

// Round 8
// 162.733 us; speedup vs baseline: 1.4010x; 1.0533x over previous
//
#include <hip/hip_runtime.h>

#define HW (512 * 512)
#define GD 200
#define NS 9
#define NF 8
#define NPB 32              // rays per block -> values rows are exactly one 128 B line
#define BT 320              // 5 waves; tids 0..287 active: r=tid/9 (0..31), s=tid%9
#define P 33                // vbuf padded leading dim

__global__ __launch_bounds__(BT) void fusion_gather_kernel(
    const float* __restrict__ vpoints,
    const float* __restrict__ veye,
    const float* __restrict__ grid,
    const float* __restrict__ empty_value,
    float* __restrict__ out_values,   // [72][HW]
    float* __restrict__ out_pn,       // [HW][9][3]
    float* __restrict__ out_dirs)     // [HW][3]
{
    __shared__ float vbuf[NS * NF * P];     // [72][33] staged values, ~9.5 KB
    __shared__ float pnbuf[NPB * 27];       // [r][s][c] 3456 B
    __shared__ float dirbuf[NPB * 3];       // 384 B ; total ~13.3 KB -> 6+ blocks/CU

    int tid = threadIdx.x;
    int n0 = blockIdx.x * NPB;              // HW % NPB == 0: no tail

    if (tid < NPB * NS) {
        int r = tid / 9;
        int s = tid - r * 9;
        int n = n0 + r;

        float px = vpoints[n * 3 + 0];
        float py = vpoints[n * 3 + 1];
        float pz = vpoints[n * 3 + 2];
        float ex = veye[0], ey = veye[1], ez = veye[2];

        float dx = px - ex, dy = py - ey, dz = pz - ez;
        float inv = 1.0f / sqrtf(dx * dx + dy * dy + dz * dz);
        dx *= inv; dy *= inv; dz *= inv;

        if (s == 0) {
            dirbuf[r * 3 + 0] = dx;
            dirbuf[r * 3 + 1] = dy;
            dirbuf[r * 3 + 2] = dz;
        }

        float off = (float)(s - NS / 2);
        float cx = px + off * dx;
        float cy = py + off * dy;
        float cz = pz + off * dz;

        pnbuf[r * 27 + s * 3 + 0] = cx - (floorf(cx) + 0.5f);
        pnbuf[r * 27 + s * 3 + 1] = cy - (floorf(cy) + 0.5f);
        pnbuf[r * 27 + s * 3 + 2] = cz - (floorf(cz) + 0.5f);

        bool valid = (cx >= 0.0f) && (cx < (float)GD) &&
                     (cy >= 0.0f) && (cy < (float)GD) &&
                     (cz >= 0.0f) && (cz < (float)GD);

        // reference: p = pts + 1 into edge-padded grid; padded idx j -> grid[clamp(j-1,0,199)]
        // Clamp unconditionally; invalid lanes load in-bounds, result replaced at store.
        float p0 = cx + 1.0f, p1 = cy + 1.0f, p2 = cz + 1.0f;
        float f0 = floorf(p0), f1 = floorf(p1), f2 = floorf(p2);
        float d0 = p0 - f0, d1 = p1 - f1, d2 = p2 - f2;
        int bx = (int)f0, by = (int)f1, bz = (int)f2;
        int X0 = min(max(bx - 1, 0), GD - 1), X1 = min(max(bx, 0), GD - 1);
        int Y0 = min(max(by - 1, 0), GD - 1), Y1 = min(max(by, 0), GD - 1);
        int Z0 = min(max(bz - 1, 0), GD - 1), Z1 = min(max(bz, 0), GD - 1);

        const float4* __restrict__ g4 = (const float4*)grid;

        // ---- load phase: all 16 independent 16B gathers before any consume ----
        int col[4];
        col[0] = (X0 * GD + Y0) * GD;
        col[1] = (X0 * GD + Y1) * GD;
        col[2] = (X1 * GD + Y0) * GD;
        col[3] = (X1 * GD + Y1) * GD;

        float4 c[16];
#pragma unroll
        for (int q = 0; q < 4; ++q) {
            c[q * 4 + 0] = g4[(size_t)(col[q] + Z0) * 2 + 0];
            c[q * 4 + 1] = g4[(size_t)(col[q] + Z0) * 2 + 1];
            c[q * 4 + 2] = g4[(size_t)(col[q] + Z1) * 2 + 0];
            c[q * 4 + 3] = g4[(size_t)(col[q] + Z1) * 2 + 1];
        }

        float wx0 = 1.0f - d0, wy0 = 1.0f - d1, wz0 = 1.0f - d2;
        float wq[4] = {wx0 * wy0, wx0 * d1, d0 * wy0, d0 * d1};

        float acc[NF];
#pragma unroll
        for (int f = 0; f < NF; ++f) acc[f] = 0.0f;

#pragma unroll
        for (int q = 0; q < 4; ++q) {
            float w0 = wq[q] * wz0, w1 = wq[q] * d2;
            acc[0] += w0 * c[q * 4 + 0].x + w1 * c[q * 4 + 2].x;
            acc[1] += w0 * c[q * 4 + 0].y + w1 * c[q * 4 + 2].y;
            acc[2] += w0 * c[q * 4 + 0].z + w1 * c[q * 4 + 2].z;
            acc[3] += w0 * c[q * 4 + 0].w + w1 * c[q * 4 + 2].w;
            acc[4] += w0 * c[q * 4 + 1].x + w1 * c[q * 4 + 3].x;
            acc[5] += w0 * c[q * 4 + 1].y + w1 * c[q * 4 + 3].y;
            acc[6] += w0 * c[q * 4 + 1].z + w1 * c[q * 4 + 3].z;
            acc[7] += w0 * c[q * 4 + 1].w + w1 * c[q * 4 + 3].w;
        }

        float ev[NF];
#pragma unroll
        for (int f = 0; f < NF; ++f) ev[f] = empty_value[f];

#pragma unroll
        for (int f = 0; f < NF; ++f)
            vbuf[(s * NF + f) * P + r] = valid ? acc[f] : ev[f];
    }

    __syncthreads();

    // ---- block-coalesced writeout ----
    // values: 72 rows x 32 cols = 2304 floats; each store covers full 128 B lines
#pragma unroll
    for (int j = 0; j < 8; ++j) {
        int idx = tid + j * BT;
        if (idx < NS * NF * NPB) {
            int row = idx >> 5;
            int colv = idx & 31;
            __builtin_nontemporal_store(vbuf[row * P + colv],
                                        &out_values[(size_t)row * HW + n0 + colv]);
        }
    }
    // pn: 864 floats contiguous
    const size_t pn_base = (size_t)n0 * 27;
#pragma unroll
    for (int j = 0; j < 3; ++j) {
        int idx = tid + j * BT;
        if (idx < NPB * 27)
            __builtin_nontemporal_store(pnbuf[idx], &out_pn[pn_base + idx]);
    }
    if (tid < NPB * 3)
        __builtin_nontemporal_store(dirbuf[tid], &out_dirs[(size_t)n0 * 3 + tid]);
}

extern "C" void kernel_launch(void* const* d_in, const int* in_sizes, int n_in,
                              void* d_out, int out_size, void* d_ws, size_t ws_size,
                              hipStream_t stream) {
    const float* vpoints = (const float*)d_in[0];
    const float* veye = (const float*)d_in[1];
    // d_in[2] = depth: unused (shape only)
    const float* grid = (const float*)d_in[3];
    const float* empty_value = (const float*)d_in[4];

    float* out = (float*)d_out;
    float* out_values = out;                          // 72 * HW
    float* out_pn = out + (size_t)NS * NF * HW;       // HW * 9 * 3
    float* out_dirs = out_pn + (size_t)HW * NS * 3;   // HW * 3

    dim3 block(BT);
    dim3 grid_dim(HW / NPB);
    hipLaunchKernelGGL(fusion_gather_kernel, grid_dim, block, 0, stream,
                       vpoints, veye, grid, empty_value,
                       out_values, out_pn, out_dirs);
}

// Round 9
// 158.076 us; speedup vs baseline: 1.4422x; 1.0295x over previous
//
#include <hip/hip_runtime.h>

#define HW (512 * 512)
#define GD 200
#define NS 9
#define NF 8
#define NPB 64              // rays per block
#define BT (NPB * NS)       // 576 threads = 9 waves; wave = ~7 rays x all 9 samples

__global__ __launch_bounds__(BT) void fusion_gather_kernel(
    const float* __restrict__ vpoints,
    const float* __restrict__ veye,
    const float* __restrict__ grid,
    const float* __restrict__ empty_value,
    float* __restrict__ out_values,   // [72][HW]
    float* __restrict__ out_pn,       // [HW][9][3]
    float* __restrict__ out_dirs)     // [HW][3]
{
    __shared__ float vp[NPB * 3];            // staged vpoints
    __shared__ float pnbuf[NPB * NS * 3];    // [r][s][c] stride 27
    __shared__ float dirbuf[NPB * 3];
    __shared__ float vbuf[NS * NF * 65];     // [72][65] padded: bank = (row+col)%32

    int tid = threadIdx.x;
    int n0 = blockIdx.x * NPB;

    if (tid < NPB * 3) vp[tid] = vpoints[(size_t)n0 * 3 + tid];
    __syncthreads();

    int r = tid / NS;          // ray 0..63 (~7 per wave)
    int s = tid - r * NS;      // sample 0..8

    float px = vp[r * 3 + 0];
    float py = vp[r * 3 + 1];
    float pz = vp[r * 3 + 2];
    float ex = veye[0], ey = veye[1], ez = veye[2];

    float dx = px - ex, dy = py - ey, dz = pz - ez;
    float inv = 1.0f / sqrtf(dx * dx + dy * dy + dz * dz);
    dx *= inv; dy *= inv; dz *= inv;

    if (s == 0) {
        dirbuf[r * 3 + 0] = dx;
        dirbuf[r * 3 + 1] = dy;
        dirbuf[r * 3 + 2] = dz;
    }

    float off = (float)(s - NS / 2);
    float cx = px + off * dx;
    float cy = py + off * dy;
    float cz = pz + off * dz;

    pnbuf[r * 27 + s * 3 + 0] = cx - (floorf(cx) + 0.5f);
    pnbuf[r * 27 + s * 3 + 1] = cy - (floorf(cy) + 0.5f);
    pnbuf[r * 27 + s * 3 + 2] = cz - (floorf(cz) + 0.5f);

    bool valid = (cx >= 0.0f) && (cx < (float)GD) &&
                 (cy >= 0.0f) && (cy < (float)GD) &&
                 (cz >= 0.0f) && (cz < (float)GD);

    // reference: p = pts + 1 into edge-padded grid; padded idx j -> grid[clamp(j-1,0,199)]
    // Clamp unconditionally; invalid lanes load in-bounds, result replaced at store.
    float p0 = cx + 1.0f, p1 = cy + 1.0f, p2 = cz + 1.0f;
    float f0 = floorf(p0), f1 = floorf(p1), f2 = floorf(p2);
    float d0 = p0 - f0, d1 = p1 - f1, d2 = p2 - f2;
    int bx = (int)f0, by = (int)f1, bz = (int)f2;
    int X0 = min(max(bx - 1, 0), GD - 1), X1 = min(max(bx, 0), GD - 1);
    int Y0 = min(max(by - 1, 0), GD - 1), Y1 = min(max(by, 0), GD - 1);
    int Z0 = min(max(bz - 1, 0), GD - 1), Z1 = min(max(bz, 0), GD - 1);

    const float4* __restrict__ g4 = (const float4*)grid;

    // ---- load phase: all 16 independent 16B gathers issued before any consume ----
    int col[4];
    col[0] = (X0 * GD + Y0) * GD;
    col[1] = (X0 * GD + Y1) * GD;
    col[2] = (X1 * GD + Y0) * GD;
    col[3] = (X1 * GD + Y1) * GD;

    float4 c[16];
#pragma unroll
    for (int q = 0; q < 4; ++q) {
        c[q * 4 + 0] = g4[(size_t)(col[q] + Z0) * 2 + 0];
        c[q * 4 + 1] = g4[(size_t)(col[q] + Z0) * 2 + 1];
        c[q * 4 + 2] = g4[(size_t)(col[q] + Z1) * 2 + 0];
        c[q * 4 + 3] = g4[(size_t)(col[q] + Z1) * 2 + 1];
    }

    float wx0 = 1.0f - d0, wx1 = d0;
    float wy0 = 1.0f - d1, wy1 = d1;
    float wz0 = 1.0f - d2, wz1 = d2;
    float wq[4];
    wq[0] = wx0 * wy0; wq[1] = wx0 * wy1; wq[2] = wx1 * wy0; wq[3] = wx1 * wy1;

    float acc[NF];
#pragma unroll
    for (int f = 0; f < NF; ++f) acc[f] = 0.0f;

#pragma unroll
    for (int q = 0; q < 4; ++q) {
        float w0 = wq[q] * wz0, w1 = wq[q] * wz1;
        acc[0] += w0 * c[q * 4 + 0].x + w1 * c[q * 4 + 2].x;
        acc[1] += w0 * c[q * 4 + 0].y + w1 * c[q * 4 + 2].y;
        acc[2] += w0 * c[q * 4 + 0].z + w1 * c[q * 4 + 2].z;
        acc[3] += w0 * c[q * 4 + 0].w + w1 * c[q * 4 + 2].w;
        acc[4] += w0 * c[q * 4 + 1].x + w1 * c[q * 4 + 3].x;
        acc[5] += w0 * c[q * 4 + 1].y + w1 * c[q * 4 + 3].y;
        acc[6] += w0 * c[q * 4 + 1].z + w1 * c[q * 4 + 3].z;
        acc[7] += w0 * c[q * 4 + 1].w + w1 * c[q * 4 + 3].w;
    }

    float ev[NF];
#pragma unroll
    for (int f = 0; f < NF; ++f) ev[f] = empty_value[f];

    // stage values: vbuf[(s*8+f)*65 + r]; 65 ≡ 1 (mod 32) -> bank spread, worst 2-way (free)
#pragma unroll
    for (int f = 0; f < NF; ++f)
        vbuf[(s * NF + f) * 65 + r] = valid ? acc[f] : ev[f];

    __syncthreads();

    // ---- block-coalesced writeout ----
    // values: 72 rows x 64; per k each wave stores one full row (256 B contiguous)
    {
        int col_ = tid & 63;
        int w = tid >> 6;
#pragma unroll
        for (int k = 0; k < 8; ++k) {
            int row = w + k * NS;
            __builtin_nontemporal_store(vbuf[row * 65 + col_],
                                        &out_values[(size_t)row * HW + n0 + col_]);
        }
    }
    // pn: 1728 floats = 3/thread
    const size_t pn_base = (size_t)n0 * (NS * 3);
#pragma unroll
    for (int k = 0; k < 3; ++k) {
        int idx = tid + k * BT;
        __builtin_nontemporal_store(pnbuf[idx], &out_pn[pn_base + idx]);
    }
    if (tid < NPB * 3)
        __builtin_nontemporal_store(dirbuf[tid], &out_dirs[(size_t)n0 * 3 + tid]);
}

extern "C" void kernel_launch(void* const* d_in, const int* in_sizes, int n_in,
                              void* d_out, int out_size, void* d_ws, size_t ws_size,
                              hipStream_t stream) {
    const float* vpoints = (const float*)d_in[0];
    const float* veye = (const float*)d_in[1];
    // d_in[2] = depth: unused (shape only)
    const float* grid = (const float*)d_in[3];
    const float* empty_value = (const float*)d_in[4];

    float* out = (float*)d_out;
    float* out_values = out;                          // 72 * HW
    float* out_pn = out + (size_t)NS * NF * HW;       // HW * 9 * 3
    float* out_dirs = out_pn + (size_t)HW * NS * 3;   // HW * 3

    dim3 block(BT);
    dim3 grid_dim(HW / NPB);
    hipLaunchKernelGGL(fusion_gather_kernel, grid_dim, block, 0, stream,
                       vpoints, veye, grid, empty_value,
                       out_values, out_pn, out_dirs);
}